// Round 7
// baseline (575.070 us; speedup 1.0000x reference)
//
#include <hip/hip_runtime.h>

#define DM   1024
#define LSEQ 512
#define NBK  192   // B*3
#define NCH  8     // L-chunks of 64 rows
#define HDIM 1024

// ws layout (floats):
//   [0..3]   = w (softmax weights)
//   [4..195] = cnts (int, per bk)
//   [196]    = flag (mask layout: 1=int32, 0=bool bytes)
//   [256 .. 256+1536*1024)              = part  (raw per-(bk,ch) sums, 6 MB)
//   [256+1536*1024 .. +65536)           = y     (combined pooled vector)
#define PART_OFF 256
#define Y_OFF    (256 + 1536 * 1024)

// ---------------------------------------------------------------------------
// Kernel 1: block 0 = mask-format detect (verified R3/R6); block 1 = softmax
// combination weights w (verified R3/R6).
// ---------------------------------------------------------------------------
__global__ __launch_bounds__(256) void detectw_kernel(
    const unsigned* __restrict__ m, const float* __restrict__ gf,
    const float* __restrict__ Wc, const float* __restrict__ bc,
    int* __restrict__ flag, float* __restrict__ w)
{
    const int t = threadIdx.x;
    if (blockIdx.x == 0) {
        __shared__ int s[256];
        unsigned any = 0;
        for (int i = t; i < (NBK * LSEQ / 4); i += 256)
            any |= m[i] & 0xFFFFFF00u;
        s[t] = (any != 0);
        __syncthreads();
        for (int sf = 128; sf > 0; sf >>= 1) {
            if (t < sf) s[t] |= s[t + sf];
            __syncthreads();
        }
        if (t == 0) *flag = (s[0] == 0) ? 1 : 0;
    } else {
        __shared__ float sz0[256], sz1[256], sz2[256];
        float p0 = 0.f, p1 = 0.f, p2 = 0.f;
        #pragma unroll
        for (int j = 0; j < 4; ++j) {
            float g = gf[t * 4 + j];
            p0 += Wc[0 * DM + t * 4 + j] * g;
            p1 += Wc[1 * DM + t * 4 + j] * g;
            p2 += Wc[2 * DM + t * 4 + j] * g;
        }
        sz0[t] = p0; sz1[t] = p1; sz2[t] = p2;
        __syncthreads();
        for (int s = 128; s > 0; s >>= 1) {
            if (t < s) { sz0[t] += sz0[t+s]; sz1[t] += sz1[t+s]; sz2[t] += sz2[t+s]; }
            __syncthreads();
        }
        if (t == 0) {
            float z0 = sz0[0] + bc[0], z1 = sz1[0] + bc[1], z2 = sz2[0] + bc[2];
            float mx = fmaxf(z0, fmaxf(z1, z2));
            float e0 = expf(z0 - mx), e1 = expf(z1 - mx), e2 = expf(z2 - mx);
            float inv = 1.0f / (e0 + e1 + e2);
            w[0] = e0 * inv; w[1] = e1 * inv; w[2] = e2 * inv;
        }
    }
}

// ---------------------------------------------------------------------------
// Kernel 2 (v2, atomic-free): block (bk,ch) computes len inline from its mask
// row (monotone mask => len = #zeros), streams its valid 64-row chunk, and
// stores RAW float4 partial sums to part[bid]. No atomics, no zero-init dep.
// ch==0 block also publishes cnts[bk] for the reduce/out stages.
// ---------------------------------------------------------------------------
__global__ __launch_bounds__(256) void pool2_kernel(
    const float4* __restrict__ x4, const unsigned char* __restrict__ mask,
    const int* __restrict__ flagp, float4* __restrict__ part,
    int* __restrict__ cnts)
{
    __shared__ int sc[256];
    const int bid = blockIdx.x;
    const int bk  = bid >> 3;
    const int ch  = bid & 7;
    const int t   = threadIdx.x;

    int c = 0;
    if (*flagp) {  // int32 mask: row of 512 ints
        const unsigned* row = (const unsigned*)mask + bk * LSEQ;
        c = (int)(row[t] == 0) + (int)(row[t + 256] == 0);
    } else {       // bool mask: row of 512 bytes = 128 words
        if (t < 128) {
            unsigned u = ((const unsigned*)mask)[bk * 128 + t];
            c = (int)((u & 0xFFu) == 0) + (int)((u & 0xFF00u) == 0)
              + (int)((u & 0xFF0000u) == 0) + (int)((u & 0xFF000000u) == 0);
        }
    }
    sc[t] = c;
    __syncthreads();
    for (int s = 128; s > 0; s >>= 1) {
        if (t < s) sc[t] += sc[t + s];
        __syncthreads();
    }
    const int len = sc[0];  // valid after the loop's trailing __syncthreads
    if (ch == 0 && t == 0) cnts[bk] = len;

    const int l0 = ch << 6;
    if (l0 >= len) return;
    const int nrows = min(64, len - l0);

    const float4* xp = x4 + ((bk * LSEQ + l0) * (DM / 4)) + t;

    float ax0=0.f, ay0=0.f, az0=0.f, aw0=0.f;
    float ax1=0.f, ay1=0.f, az1=0.f, aw1=0.f;
    int r = 0;
    for (; r + 2 <= nrows; r += 2) {
        float4 v0 = xp[(r    ) * (DM / 4)];
        float4 v1 = xp[(r + 1) * (DM / 4)];
        ax0 += v0.x; ay0 += v0.y; az0 += v0.z; aw0 += v0.w;
        ax1 += v1.x; ay1 += v1.y; az1 += v1.z; aw1 += v1.w;
    }
    if (r < nrows) {
        float4 v0 = xp[r * (DM / 4)];
        ax0 += v0.x; ay0 += v0.y; az0 += v0.z; aw0 += v0.w;
    }
    float4 v;
    v.x = ax0 + ax1; v.y = ay0 + ay1; v.z = az0 + az1; v.w = aw0 + aw1;
    part[bid * 256 + t] = v;   // coalesced, non-atomic
}

// ---------------------------------------------------------------------------
// Kernel 3: y[b,d] = sum_k (w_k/len_k) * sum_{valid ch} part[(b,k,ch)][d].
// grid 64 x 256; thread owns (b, one float4 of d). <=24 coalesced float4
// loads/thread from L2 (part only 6 MB); poisoned ch>=nch slots never read.
// ---------------------------------------------------------------------------
__global__ __launch_bounds__(256) void reduce_kernel(
    const float4* __restrict__ part, const float* __restrict__ w,
    const int* __restrict__ cnts, float4* __restrict__ y4)
{
    const int b = blockIdx.x;
    const int t = threadIdx.x;
    float4 acc; acc.x = acc.y = acc.z = acc.w = 0.f;
    #pragma unroll
    for (int k = 0; k < 3; ++k) {
        const int bk  = b * 3 + k;
        const int len = cnts[bk];
        const int nch = (len + 63) >> 6;
        const float s = w[k] / (float)len;
        const float4* p = part + bk * 8 * 256 + t;
        for (int chv = 0; chv < nch; ++chv) {
            float4 v = p[chv * 256];
            acc.x += s * v.x; acc.y += s * v.y;
            acc.z += s * v.z; acc.w += s * v.w;
        }
    }
    y4[b * 256 + t] = acc;
}

// ---------------------------------------------------------------------------
// Kernel 4 (verified R6): feature[b,h] = dot(y[b,:], W_proj[h,:]) + b_proj.
// Block = 4 h x 64 b; 128-col K-chunks staged in LDS stride 129 (2 lanes/bank
// = free); W wave-uniform broadcast, read once total; LDS-transpose epilogue.
// ---------------------------------------------------------------------------
__global__ __launch_bounds__(256) void out_kernel(
    const float4* __restrict__ y4, const float4* __restrict__ W4,
    const float4* __restrict__ bp4, float4* __restrict__ out4)
{
    __shared__ float ylds[64 * 129];
    const int t  = threadIdx.x;
    const int b  = t & 63;
    const int hh = t >> 6;
    const int h  = (blockIdx.x << 2) + hh;

    float acc = 0.f;
    for (int c = 0; c < 8; ++c) {
        __syncthreads();
        #pragma unroll
        for (int j = 0; j < 8; ++j) {
            int flat = j * 256 + t;          // 0..2047
            int row  = flat >> 5;            // 0..63
            int col4 = flat & 31;            // 0..31
            float4 v = y4[row * 256 + c * 32 + col4];
            float* p = &ylds[row * 129 + (col4 << 2)];
            p[0] = v.x; p[1] = v.y; p[2] = v.z; p[3] = v.w;
        }
        __syncthreads();
        const float* yr = &ylds[b * 129];
        #pragma unroll
        for (int j = 0; j < 32; ++j) {
            float4 wv = W4[h * 256 + c * 32 + j];
            int i = j << 2;
            acc += yr[i]     * wv.x + yr[i + 1] * wv.y
                 + yr[i + 2] * wv.z + yr[i + 3] * wv.w;
        }
    }

    __syncthreads();
    ylds[hh * 64 + b] = acc;
    __syncthreads();
    if (t < 64) {
        float4 bv = bp4[blockIdx.x];
        float4 v;
        v.x = ylds[0 * 64 + t] + bv.x;
        v.y = ylds[1 * 64 + t] + bv.y;
        v.z = ylds[2 * 64 + t] + bv.z;
        v.w = ylds[3 * 64 + t] + bv.w;
        out4[t * (HDIM / 4) + blockIdx.x] = v;
    }
}

extern "C" void kernel_launch(void* const* d_in, const int* in_sizes, int n_in,
                              void* d_out, int out_size, void* d_ws, size_t ws_size,
                              hipStream_t stream) {
    const float*         gf   = (const float*)d_in[0];         // (DM,)
    const float*         x    = (const float*)d_in[1];         // (B,3,L,DM)
    const unsigned char* mask = (const unsigned char*)d_in[2]; // (B,3,L)
    const float*         Wp   = (const float*)d_in[3];         // (H,DM)
    const float*         bp   = (const float*)d_in[4];         // (H,)
    const float*         Wc   = (const float*)d_in[5];         // (3,DM)
    const float*         bc   = (const float*)d_in[6];         // (3,)
    float* out = (float*)d_out;                                // (B,H)

    float*  wsf  = (float*)d_ws;
    float*  w    = wsf;
    int*    cnts = (int*)(wsf + 4);
    int*    flag = (int*)(wsf + 196);
    float4* part = (float4*)(wsf + PART_OFF);  // byte 1024, 16B-aligned
    float*  y    = wsf + Y_OFF;                // byte 6292480, 16B-aligned

    detectw_kernel<<<2, 256, 0, stream>>>((const unsigned*)mask, gf, Wc, bc,
                                          flag, w);
    pool2_kernel<<<NBK * NCH, 256, 0, stream>>>((const float4*)x, mask, flag,
                                                part, cnts);
    reduce_kernel<<<64, 256, 0, stream>>>((const float4*)part, w, cnts,
                                          (float4*)y);
    out_kernel<<<HDIM / 4, 256, 0, stream>>>((const float4*)y, (const float4*)Wp,
                                             (const float4*)bp, (float4*)out);
}